// Round 17
// baseline (406.826 us; speedup 1.0000x reference)
//
#include <hip/hip_runtime.h>
#include <hip/hip_bf16.h>

typedef __bf16 bf16x8 __attribute__((ext_vector_type(8)));
typedef float  f32x4  __attribute__((ext_vector_type(4)));

#define LRELU_ALPHA 0.2f
#define LOG2E 1.44269504088896340736f

__device__ __forceinline__ float fexp2(float x) {
#if __has_builtin(__builtin_amdgcn_exp2f)
    return __builtin_amdgcn_exp2f(x);
#else
    float r; asm("v_exp_f32 %0, %1" : "=v"(r) : "v"(x)); return r;
#endif
}

// ---------------------------------------------------------------------------
// Kernel 1: h = inp @ W (8 rows/block) -> hb (bf16), f1/f2 prescaled by log2e.
// ---------------------------------------------------------------------------
__global__ __launch_bounds__(128) void gat_prep(
    const float* __restrict__ inp, const float* __restrict__ W,
    const float* __restrict__ a,
    __bf16* __restrict__ hb, float* __restrict__ f1, float* __restrict__ f2)
{
    const int r0 = blockIdx.x << 3;
    const int d  = threadIdx.x;
    __shared__ float sIn[8][128];
    __shared__ float sRed[8][4];
    #pragma unroll
    for (int r = 0; r < 8; ++r)
        sIn[r][d] = inp[(size_t)(r0 + r) * 128 + d];
    __syncthreads();

    float acc[8] = {0.f,0.f,0.f,0.f,0.f,0.f,0.f,0.f};
    #pragma unroll 4
    for (int k = 0; k < 128; ++k) {
        float wv = W[k * 128 + d];
        #pragma unroll
        for (int r = 0; r < 8; ++r) acc[r] += sIn[r][k] * wv;
    }

    const float a1 = a[d], a2 = a[128 + d];
    const int wv = d >> 6;
    #pragma unroll
    for (int r = 0; r < 8; ++r) {
        hb[(size_t)(r0 + r) * 128 + d] = (__bf16)acc[r];
        float t1 = acc[r] * a1;
        float t2 = acc[r] * a2;
        #pragma unroll
        for (int m = 1; m < 64; m <<= 1) {
            t1 += __shfl_xor(t1, m);
            t2 += __shfl_xor(t2, m);
        }
        if ((d & 63) == 0) { sRed[r][wv] = t1; sRed[r][2 + wv] = t2; }
    }
    __syncthreads();
    if (d < 8) {
        f1[r0 + d] = (sRed[d][0] + sRed[d][1]) * LOG2E;
        f2[r0 + d] = (sRed[d][2] + sRed[d][3]) * LOG2E;
    }
}

// ---------------------------------------------------------------------------
// Kernel 2: per-batch max of (prescaled) f1
// ---------------------------------------------------------------------------
__global__ __launch_bounds__(256) void gat_f1max(
    const float* __restrict__ f1, float* __restrict__ f1max)
{
    const int b = blockIdx.x;
    const int t = threadIdx.x;
    float m = -1e30f;
    for (int j = t; j < 2048; j += 256) m = fmaxf(m, f1[b * 2048 + j]);
    #pragma unroll
    for (int k = 1; k < 64; k <<= 1) m = fmaxf(m, __shfl_xor(m, k));
    __shared__ float sm[4];
    if ((t & 63) == 0) sm[t >> 6] = m;
    __syncthreads();
    if (t == 0) f1max[b] = fmaxf(fmaxf(sm[0], sm[1]), fmaxf(sm[2], sm[3]));
}

// ---------------------------------------------------------------------------
// Kernel 3: hb -> pack (fragment-major bf16 B-operands); see v5 comment.
// ---------------------------------------------------------------------------
__global__ __launch_bounds__(256) void gat_pack(
    const __bf16* __restrict__ hb, __bf16* __restrict__ pack)
{
    __shared__ __bf16 tile[64][72];
    const int tid = threadIdx.x;
    const int bidx = blockIdx.x;         // 512 blocks
    const int b  = bidx >> 6;
    const int tI = bidx & 63;
    const int n0 = (tI >> 1) << 6;
    const int d0 = (tI & 1) << 6;
    #pragma unroll
    for (int pass = 0; pass < 2; ++pass) {
        int row = (tid >> 3) + (pass << 5);
        int c   = (tid & 7) << 3;
        *(bf16x8*)&tile[row][c] =
            *(const bf16x8*)(hb + (size_t)(b * 2048 + n0 + row) * 128 + d0 + c);
    }
    __syncthreads();
    const int lane = tid & 63;
    const int il = lane & 15;
    const int kg = lane >> 4;
    #pragma unroll
    for (int pass = 0; pass < 2; ++pass) {
        const int f  = (tid >> 6) + (pass << 2);
        const int Dl = f >> 1;
        const int jh = f & 1;
        union { __bf16 e[8]; bf16x8 v; } u;
        #pragma unroll
        for (int e = 0; e < 8; ++e)
            u.e[e] = tile[(jh << 5) + (kg << 3) + e][(Dl << 4) + il];
        const size_t off = (((size_t)(b << 5) + (n0 >> 6)) << 13)
                         + ((size_t)((((d0 >> 4) + Dl) << 1) | jh) << 9)
                         + (lane << 3);
        *(bf16x8*)(pack + off) = u.v;
    }
}

// ---------------------------------------------------------------------------
// Kernel 3b: adj (128 MB) -> tb consumer-major bitmask (4 MB). (v15, passed)
// ---------------------------------------------------------------------------
__global__ __launch_bounds__(256, 4) void gat_adjpack(
    const int* __restrict__ adj, uint4* __restrict__ tb)
{
    const int tid  = threadIdx.x;
    const int rloc = tid >> 4;
    const int jq   = (tid >> 2) & 3;
    const int kg   = tid & 3;
    const size_t grow = (size_t)blockIdx.x * 16 + rloc;   // 1024 blocks
    const int* base = adj + (grow << 11) + (jq << 9) + (kg << 3);

    int4 A[8], B[8];
    #pragma unroll
    for (int i = 0; i < 8; ++i)
        A[i] = *(const int4*)(base + (i >> 1) * 32 + (i & 1) * 4);
    #pragma unroll
    for (int i = 0; i < 8; ++i)
        B[i] = *(const int4*)(base + 128 + (i >> 1) * 32 + (i & 1) * 4);

    unsigned wds[4];
    #pragma unroll
    for (int W = 0; W < 4; ++W) {
        unsigned u = 0;
        #pragma unroll
        for (int i = 0; i < 8; ++i) {
            int4 v = (W & 1) ? B[i] : A[i];
            const int sh = (i >> 1) * 8 + (i & 1) * 4;
            u |= ((unsigned)(v.x > 0) << sh)
               | ((unsigned)(v.y > 0) << (sh + 1))
               | ((unsigned)(v.z > 0) << (sh + 2))
               | ((unsigned)(v.w > 0) << (sh + 3));
        }
        wds[W] = u;
        if (W < 2) {
            #pragma unroll
            for (int i = 0; i < 8; ++i) {
                int4 nv = *(const int4*)(base + (W + 2) * 128 + (i >> 1) * 32 + (i & 1) * 4);
                if (W & 1) B[i] = nv; else A[i] = nv;
            }
        }
    }
    uint4 o; o.x = wds[0]; o.y = wds[1]; o.z = wds[2]; o.w = wds[3];
    tb[((grow << 2) + jq) * 4 + kg] = o;
}

// ---------------------------------------------------------------------------
// Kernel 4: ABLATION TEMPLATE of the v15 attention kernel.
// V=0 full (real output) | V=1 no-MFMA | V=2 no-P | V=3 no-B | V=4 no-barrier
// R = repeat count (acc re-initialized per repeat -> V0 result exact).
// ---------------------------------------------------------------------------
#if __has_builtin(__builtin_amdgcn_global_load_lds)
#define STAGE(T, BUF)                                                         \
    __builtin_amdgcn_global_load_lds(                                         \
        (const __attribute__((address_space(1))) void*)                       \
            (pkbase + (((T) >> 1) * 16384) + (((T) & 1) * 1024)),             \
        (__attribute__((address_space(3))) void*)(&Bs[BUF][w << 9]),          \
        16, 0, 0)
#else
#define STAGE(T, BUF) do {                                                    \
    bf16x8 _tmp = *(const bf16x8*)(pkbase + (((T) >> 1) * 16384)              \
                                   + (((T) & 1) * 1024));                     \
    *(bf16x8*)&Bs[BUF][(w << 9) + (lane << 3)] = _tmp;                        \
} while (0)
#endif

template<int V, int R>
__global__ __launch_bounds__(512, 4) void gat_attn_t(
    const uint4* __restrict__ tb, const __bf16* __restrict__ pack,
    const float* __restrict__ f1g, const float* __restrict__ f2g,
    const float* __restrict__ f1maxg,
    float* __restrict__ out, __bf16* __restrict__ pO, float* __restrict__ pD)
{
    const int bid = ((blockIdx.x & 7) << 6) | (blockIdx.x >> 3);  // batch<->XCD
    const int b  = bid >> 6;
    const int rg = (bid >> 2) & 15;
    const int jq = bid & 3;
    const int i0 = rg << 7;              // 128 rows per block
    const int jb = jq << 9;              // 512-j quarter
    const int tid = threadIdx.x;

    __shared__ alignas(16) float us[512];
    __shared__ alignas(16) float vs[512];
    __shared__ alignas(16) __bf16 Bs[2][4096];

    const int w    = tid >> 6;
    const int lane = tid & 63;
    const int il   = lane & 15;
    const int kg   = lane >> 4;
    const int row  = i0 + (w << 4) + il;
    const size_t grow = (size_t)(b << 11) + row;

    const uint4 mask = tb[((grow << 2) + jq) * 4 + kg];

    if (tid < 128) {
        float4 fv = *(const float4*)&f1g[(b << 11) + jb + (tid << 2)];
        float4 uu, vv;
        uu.x = fexp2(fv.x); uu.y = fexp2(fv.y);
        uu.z = fexp2(fv.z); uu.w = fexp2(fv.w);
        vv.x = fexp2(LRELU_ALPHA * fv.x); vv.y = fexp2(LRELU_ALPHA * fv.y);
        vv.z = fexp2(LRELU_ALPHA * fv.z); vv.w = fexp2(LRELU_ALPHA * fv.w);
        *(float4*)&us[tid << 2] = uu;
        *(float4*)&vs[tid << 2] = vv;
    }

    const float fm  = f1maxg[b];
    const float f2v = f2g[grow];
    const float zM  = f2v + fm;
    const float M   = fmaxf(zM, LRELU_ALPHA * zM);        // exact: p <= 1
    const float ai_ = fexp2(f2v - M);
    const float bi_ = fexp2(__builtin_fmaf(LRELU_ALPHA, f2v, -M));

    const char* pkbase = (const char*)pack
        + ((size_t)(b * 32 + jq * 8)) * 16384
        + (size_t)w * 2048
        + (size_t)lane * 16;

    f32x4 acc[8];
    f32x4 accd;
    union { __bf16 e[8]; bf16x8 v; } ones;
    #pragma unroll
    for (int x = 0; x < 8; ++x) ones.e[x] = (__bf16)1.0f;
    const bf16x8 onesv = ones.v;

    for (int rep = 0; rep < R; ++rep) {
        #pragma unroll
        for (int D = 0; D < 8; ++D) acc[D] = (f32x4){0.f, 0.f, 0.f, 0.f};
        accd = (f32x4){0.f, 0.f, 0.f, 0.f};

        if (V != 3) STAGE(0, 0);
        __syncthreads();                 // us/vs (+stage0) ready

        #pragma unroll
        for (int t = 0; t < 16; ++t) {
            const int cb = t & 1;

            if (V != 3 && t < 15) STAGE(t + 1, cb ^ 1);

            // ---- P(t) ----
            union { __bf16 e[8]; bf16x8 v; } pa;
            if (V == 2) {
                pa.v = onesv;
            } else {
                const unsigned wd = (t >> 2) == 0 ? mask.x : (t >> 2) == 1 ? mask.y
                                  : (t >> 2) == 2 ? mask.z : mask.w;
                const unsigned byte = (wd >> ((t & 3) << 3)) & 0xffu;
                const float4 u0 = *(const float4*)&us[t * 32 + (kg << 3)];
                const float4 u1 = *(const float4*)&us[t * 32 + (kg << 3) + 4];
                const float4 v0 = *(const float4*)&vs[t * 32 + (kg << 3)];
                const float4 v1 = *(const float4*)&vs[t * 32 + (kg << 3) + 4];
                pa.e[0] = (byte &   1u) ? (__bf16)fmaxf(ai_ * u0.x, bi_ * v0.x) : (__bf16)0.f;
                pa.e[1] = (byte &   2u) ? (__bf16)fmaxf(ai_ * u0.y, bi_ * v0.y) : (__bf16)0.f;
                pa.e[2] = (byte &   4u) ? (__bf16)fmaxf(ai_ * u0.z, bi_ * v0.z) : (__bf16)0.f;
                pa.e[3] = (byte &   8u) ? (__bf16)fmaxf(ai_ * u0.w, bi_ * v0.w) : (__bf16)0.f;
                pa.e[4] = (byte &  16u) ? (__bf16)fmaxf(ai_ * u1.x, bi_ * v1.x) : (__bf16)0.f;
                pa.e[5] = (byte &  32u) ? (__bf16)fmaxf(ai_ * u1.y, bi_ * v1.y) : (__bf16)0.f;
                pa.e[6] = (byte &  64u) ? (__bf16)fmaxf(ai_ * u1.z, bi_ * v1.z) : (__bf16)0.f;
                pa.e[7] = (byte & 128u) ? (__bf16)fmaxf(ai_ * u1.w, bi_ * v1.w) : (__bf16)0.f;
            }

            // ---- MFMA / sinks ----
            if (V == 1) {
                asm volatile("" :: "v"(pa.v));           // keep P live
                #pragma unroll
                for (int D = 0; D < 8; ++D) {
                    bf16x8 Bf = *(const bf16x8*)&Bs[cb][(D << 9) + (lane << 3)];
                    asm volatile("" :: "v"(Bf));         // keep B reads live
                }
            } else {
                __builtin_amdgcn_s_setprio(1);
                #pragma unroll
                for (int D = 0; D < 8; ++D) {
                    bf16x8 Bf = (V == 3) ? onesv
                              : *(const bf16x8*)&Bs[cb][(D << 9) + (lane << 3)];
                    acc[D] = __builtin_amdgcn_mfma_f32_16x16x32_bf16(pa.v, Bf, acc[D], 0, 0, 0);
                }
                accd = __builtin_amdgcn_mfma_f32_16x16x32_bf16(pa.v, onesv, accd, 0, 0, 0);
                __builtin_amdgcn_s_setprio(0);
            }

            if (t < 15 && V != 4) __syncthreads();
        }
        if (R > 1) __syncthreads();      // separate repeats
    }

    // ---- write partials ----
    const int rowg = (b << 11) + i0 + (w << 4) + (kg << 2);
    if (jq == 0) {
        #pragma unroll
        for (int r = 0; r < 4; ++r) {
            const size_t base = (((size_t)rowg + r) << 7) + il;
            #pragma unroll
            for (int D = 0; D < 8; ++D)
                out[base + (D << 4)] = acc[D][r];
        }
    } else {
        __bf16* po = pO + ((size_t)(jq - 1) << 21);
        #pragma unroll
        for (int r = 0; r < 4; ++r) {
            const size_t base = (((size_t)rowg + r) << 7) + il;
            #pragma unroll
            for (int D = 0; D < 8; ++D)
                po[base + (D << 4)] = (__bf16)acc[D][r];
        }
    }
    if (il == 0) {
        #pragma unroll
        for (int r = 0; r < 4; ++r)
            pD[(jq << 14) + rowg + r] = accd[r];
    }
}

// ---------------------------------------------------------------------------
// Kernel 5: combine 4 j-quarter partials, normalize, elu, residual.
// ---------------------------------------------------------------------------
__global__ __launch_bounds__(256) void gat_combine(
    float* io, const __bf16* __restrict__ pO,
    const float* __restrict__ pD, const __bf16* __restrict__ hb)
{
    const int idx = blockIdx.x * 256 + threadIdx.x;
    const size_t base = (size_t)idx << 3;
    const int rowAll = idx >> 4;
    const float den = pD[rowAll] + pD[16384 + rowAll]
                    + pD[32768 + rowAll] + pD[49152 + rowAll];
    const float rden = 1.0f / den;
    float4 o0a = *(const float4*)(io + base);
    float4 o0b = *(const float4*)(io + base + 4);
    bf16x8 p1 = *(const bf16x8*)(pO + base);
    bf16x8 p2 = *(const bf16x8*)(pO + (1u << 21) + base);
    bf16x8 p3 = *(const bf16x8*)(pO + (2u << 21) + base);
    bf16x8 hv = *(const bf16x8*)(hb + base);
    float res[8];
    #pragma unroll
    for (int e = 0; e < 8; ++e) {
        float o = ((e < 4) ? ((const float*)&o0a)[e] : ((const float*)&o0b)[e - 4])
                + (float)p1[e] + (float)p2[e] + (float)p3[e];
        float v  = o * rden;
        float el = (v > 0.f) ? v : (fexp2(v * LOG2E) - 1.f);
        res[e] = el + (float)hv[e];
    }
    *(float4*)(io + base)     = (float4){res[0], res[1], res[2], res[3]};
    *(float4*)(io + base + 4) = (float4){res[4], res[5], res[6], res[7]};
}

// ---------------------------------------------------------------------------
extern "C" void kernel_launch(void* const* d_in, const int* in_sizes, int n_in,
                              void* d_out, int out_size, void* d_ws, size_t ws_size,
                              hipStream_t stream)
{
    const float* inp = (const float*)d_in[0];
    const int*   adj = (const int*)d_in[1];
    const float* W   = (const float*)d_in[2];
    const float* a   = (const float*)d_in[3];
    float* out = (float*)d_out;

    // workspace layout (d_ws = 512 MB; using ~49 MB)
    char* ws = (char*)d_ws;
    __bf16* hb    = (__bf16*)ws;                          // 4 MB
    __bf16* pack  = (__bf16*)(ws + (4 << 20));            // 4 MB
    uint4*  tb    = (uint4*)(ws + (8 << 20));             // 4 MB bitmask
    __bf16* pO    = (__bf16*)(ws + (12 << 20));           // 12 MB
    float*  pD    = (float*)(ws + (24 << 20));            // 256 KB
    float*  f1    = (float*)(ws + (24 << 20) + 262144);
    float*  f2    = (float*)(ws + (24 << 20) + 262144 + 65536);
    float*  f1max = (float*)(ws + (24 << 20) + 262144 + 131072);
    // probe scratch (outputs never read)
    float*  poutF = (float*)(ws + (28 << 20));            // 8 MB
    __bf16* pOp   = (__bf16*)(ws + (36 << 20));           // 12 MB
    float*  pDp   = (float*)(ws + (48 << 20));            // 256 KB

    gat_adjpack<<<1024, 256, 0, stream>>>(adj, tb);
    gat_prep<<<2048, 128, 0, stream>>>(inp, W, a, hb, f1, f2);
    gat_f1max<<<8, 256, 0, stream>>>(f1, f1max);
    gat_pack<<<512, 256, 0, stream>>>(hb, pack);

    // real (R=2: exact output, dur > fills so counters land in top-5)
    gat_attn_t<0, 2><<<512, 512, 0, stream>>>(tb, pack, f1, f2, f1max, out, pO, pD);
    // ablation probes (R=8, scratch outputs)
    gat_attn_t<1, 8><<<512, 512, 0, stream>>>(tb, pack, f1, f2, f1max, poutF, pOp, pDp);
    gat_attn_t<2, 8><<<512, 512, 0, stream>>>(tb, pack, f1, f2, f1max, poutF, pOp, pDp);
    gat_attn_t<3, 8><<<512, 512, 0, stream>>>(tb, pack, f1, f2, f1max, poutF, pOp, pDp);
    gat_attn_t<4, 8><<<512, 512, 0, stream>>>(tb, pack, f1, f2, f1max, poutF, pOp, pDp);

    gat_combine<<<1024, 256, 0, stream>>>(out, pO, pD, hb);
}

// Round 18
// 76.575 us; speedup vs baseline: 5.3128x; 5.3128x over previous
//
#include <hip/hip_runtime.h>
#include <hip/hip_bf16.h>

typedef __bf16 bf16x8 __attribute__((ext_vector_type(8)));
typedef float  f32x4  __attribute__((ext_vector_type(4)));

#define LRELU_ALPHA 0.2f
#define LOG2E 1.44269504088896340736f

__device__ __forceinline__ float fexp2(float x) {
#if __has_builtin(__builtin_amdgcn_exp2f)
    return __builtin_amdgcn_exp2f(x);
#else
    float r; asm("v_exp_f32 %0, %1" : "=v"(r) : "v"(x)); return r;
#endif
}

// ---------------------------------------------------------------------------
// Kernel 1: h = inp @ W (8 rows/block) -> hb (bf16), f1/f2 prescaled by log2e.
// ---------------------------------------------------------------------------
__global__ __launch_bounds__(128) void gat_prep(
    const float* __restrict__ inp, const float* __restrict__ W,
    const float* __restrict__ a,
    __bf16* __restrict__ hb, float* __restrict__ f1, float* __restrict__ f2)
{
    const int r0 = blockIdx.x << 3;
    const int d  = threadIdx.x;
    __shared__ float sIn[8][128];
    __shared__ float sRed[8][4];
    #pragma unroll
    for (int r = 0; r < 8; ++r)
        sIn[r][d] = inp[(size_t)(r0 + r) * 128 + d];
    __syncthreads();

    float acc[8] = {0.f,0.f,0.f,0.f,0.f,0.f,0.f,0.f};
    #pragma unroll 4
    for (int k = 0; k < 128; ++k) {
        float wv = W[k * 128 + d];
        #pragma unroll
        for (int r = 0; r < 8; ++r) acc[r] += sIn[r][k] * wv;
    }

    const float a1 = a[d], a2 = a[128 + d];
    const int wv = d >> 6;
    #pragma unroll
    for (int r = 0; r < 8; ++r) {
        hb[(size_t)(r0 + r) * 128 + d] = (__bf16)acc[r];
        float t1 = acc[r] * a1;
        float t2 = acc[r] * a2;
        #pragma unroll
        for (int m = 1; m < 64; m <<= 1) {
            t1 += __shfl_xor(t1, m);
            t2 += __shfl_xor(t2, m);
        }
        if ((d & 63) == 0) { sRed[r][wv] = t1; sRed[r][2 + wv] = t2; }
    }
    __syncthreads();
    if (d < 8) {
        f1[r0 + d] = (sRed[d][0] + sRed[d][1]) * LOG2E;
        f2[r0 + d] = (sRed[d][2] + sRed[d][3]) * LOG2E;
    }
}

// ---------------------------------------------------------------------------
// Kernel 2: per-batch max of (prescaled) f1
// ---------------------------------------------------------------------------
__global__ __launch_bounds__(256) void gat_f1max(
    const float* __restrict__ f1, float* __restrict__ f1max)
{
    const int b = blockIdx.x;
    const int t = threadIdx.x;
    float m = -1e30f;
    for (int j = t; j < 2048; j += 256) m = fmaxf(m, f1[b * 2048 + j]);
    #pragma unroll
    for (int k = 1; k < 64; k <<= 1) m = fmaxf(m, __shfl_xor(m, k));
    __shared__ float sm[4];
    if ((t & 63) == 0) sm[t >> 6] = m;
    __syncthreads();
    if (t == 0) f1max[b] = fmaxf(fmaxf(sm[0], sm[1]), fmaxf(sm[2], sm[3]));
}

// ---------------------------------------------------------------------------
// Kernel 3: hb -> pack (fragment-major bf16 B-operands); see v5 comment.
// ---------------------------------------------------------------------------
__global__ __launch_bounds__(256) void gat_pack(
    const __bf16* __restrict__ hb, __bf16* __restrict__ pack)
{
    __shared__ __bf16 tile[64][72];
    const int tid = threadIdx.x;
    const int bidx = blockIdx.x;         // 512 blocks
    const int b  = bidx >> 6;
    const int tI = bidx & 63;
    const int n0 = (tI >> 1) << 6;
    const int d0 = (tI & 1) << 6;
    #pragma unroll
    for (int pass = 0; pass < 2; ++pass) {
        int row = (tid >> 3) + (pass << 5);
        int c   = (tid & 7) << 3;
        *(bf16x8*)&tile[row][c] =
            *(const bf16x8*)(hb + (size_t)(b * 2048 + n0 + row) * 128 + d0 + c);
    }
    __syncthreads();
    const int lane = tid & 63;
    const int il = lane & 15;
    const int kg = lane >> 4;
    #pragma unroll
    for (int pass = 0; pass < 2; ++pass) {
        const int f  = (tid >> 6) + (pass << 2);
        const int Dl = f >> 1;
        const int jh = f & 1;
        union { __bf16 e[8]; bf16x8 v; } u;
        #pragma unroll
        for (int e = 0; e < 8; ++e)
            u.e[e] = tile[(jh << 5) + (kg << 3) + e][(Dl << 4) + il];
        const size_t off = (((size_t)(b << 5) + (n0 >> 6)) << 13)
                         + ((size_t)((((d0 >> 4) + Dl) << 1) | jh) << 9)
                         + (lane << 3);
        *(bf16x8*)(pack + off) = u.v;
    }
}

// ---------------------------------------------------------------------------
// Kernel 3b: adj (128 MB) -> tb consumer-major bitmask (4 MB). (passed)
// ---------------------------------------------------------------------------
__global__ __launch_bounds__(256, 4) void gat_adjpack(
    const int* __restrict__ adj, uint4* __restrict__ tb)
{
    const int tid  = threadIdx.x;
    const int rloc = tid >> 4;
    const int jq   = (tid >> 2) & 3;
    const int kg   = tid & 3;
    const size_t grow = (size_t)blockIdx.x * 16 + rloc;   // 1024 blocks
    const int* base = adj + (grow << 11) + (jq << 9) + (kg << 3);

    int4 A[8], B[8];
    #pragma unroll
    for (int i = 0; i < 8; ++i)
        A[i] = *(const int4*)(base + (i >> 1) * 32 + (i & 1) * 4);
    #pragma unroll
    for (int i = 0; i < 8; ++i)
        B[i] = *(const int4*)(base + 128 + (i >> 1) * 32 + (i & 1) * 4);

    unsigned wds[4];
    #pragma unroll
    for (int W = 0; W < 4; ++W) {
        unsigned u = 0;
        #pragma unroll
        for (int i = 0; i < 8; ++i) {
            int4 v = (W & 1) ? B[i] : A[i];
            const int sh = (i >> 1) * 8 + (i & 1) * 4;
            u |= ((unsigned)(v.x > 0) << sh)
               | ((unsigned)(v.y > 0) << (sh + 1))
               | ((unsigned)(v.z > 0) << (sh + 2))
               | ((unsigned)(v.w > 0) << (sh + 3));
        }
        wds[W] = u;
        if (W < 2) {
            #pragma unroll
            for (int i = 0; i < 8; ++i) {
                int4 nv = *(const int4*)(base + (W + 2) * 128 + (i >> 1) * 32 + (i & 1) * 4);
                if (W & 1) B[i] = nv; else A[i] = nv;
            }
        }
    }
    uint4 o; o.x = wds[0]; o.y = wds[1]; o.z = wds[2]; o.w = wds[3];
    tb[((grow << 2) + jq) * 4 + kg] = o;
}

// ---------------------------------------------------------------------------
// Kernel 4 v16: v15 attention with counted-vmcnt pipeline (no barrier drain).
// 3 staging buffers, STAGE 2 tiles ahead; end-of-iter = s_waitcnt vmcnt(1)
// (waits STAGE(t+1), issued a full iteration earlier) + RAW s_barrier.
// Hazards: write-visible = per-wave vmcnt wait + barrier; read-done = reads
// of Bs[x] complete before that iter's end barrier (consumed by MFMA), and
// STAGE targeting x occurs ≥1 barrier later.
// ---------------------------------------------------------------------------
#if __has_builtin(__builtin_amdgcn_global_load_lds)
#define STAGE(T, BUF)                                                         \
    __builtin_amdgcn_global_load_lds(                                         \
        (const __attribute__((address_space(1))) void*)                       \
            (pkbase + (((T) >> 1) * 16384) + (((T) & 1) * 1024)),             \
        (__attribute__((address_space(3))) void*)(&Bs[BUF][w << 9]),          \
        16, 0, 0)
#else
#define STAGE(T, BUF) do {                                                    \
    bf16x8 _tmp = *(const bf16x8*)(pkbase + (((T) >> 1) * 16384)              \
                                   + (((T) & 1) * 1024));                     \
    *(bf16x8*)&Bs[BUF][(w << 9) + (lane << 3)] = _tmp;                        \
} while (0)
#endif

__global__ __launch_bounds__(512, 4) void gat_attn16(
    const uint4* __restrict__ tb, const __bf16* __restrict__ pack,
    const float* __restrict__ f1g, const float* __restrict__ f2g,
    const float* __restrict__ f1maxg,
    float* __restrict__ out, __bf16* __restrict__ pO, float* __restrict__ pD)
{
    const int bid = ((blockIdx.x & 7) << 6) | (blockIdx.x >> 3);  // batch<->XCD
    const int b  = bid >> 6;
    const int rg = (bid >> 2) & 15;
    const int jq = bid & 3;
    const int i0 = rg << 7;              // 128 rows per block
    const int jb = jq << 9;              // 512-j quarter
    const int tid = threadIdx.x;

    __shared__ alignas(16) float us[512];
    __shared__ alignas(16) float vs[512];
    __shared__ alignas(16) __bf16 Bs[3][4096];   // triple-buffered B tiles

    const int w    = tid >> 6;
    const int lane = tid & 63;
    const int il   = lane & 15;
    const int kg   = lane >> 4;
    const int row  = i0 + (w << 4) + il;
    const size_t grow = (size_t)(b << 11) + row;

    const uint4 mask = tb[((grow << 2) + jq) * 4 + kg];

    if (tid < 128) {
        float4 fv = *(const float4*)&f1g[(b << 11) + jb + (tid << 2)];
        float4 uu, vv;
        uu.x = fexp2(fv.x); uu.y = fexp2(fv.y);
        uu.z = fexp2(fv.z); uu.w = fexp2(fv.w);
        vv.x = fexp2(LRELU_ALPHA * fv.x); vv.y = fexp2(LRELU_ALPHA * fv.y);
        vv.z = fexp2(LRELU_ALPHA * fv.z); vv.w = fexp2(LRELU_ALPHA * fv.w);
        *(float4*)&us[tid << 2] = uu;
        *(float4*)&vs[tid << 2] = vv;
    }

    const float fm  = f1maxg[b];
    const float f2v = f2g[grow];
    const float zM  = f2v + fm;
    const float M   = fmaxf(zM, LRELU_ALPHA * zM);        // exact: p <= 1
    const float ai_ = fexp2(f2v - M);
    const float bi_ = fexp2(__builtin_fmaf(LRELU_ALPHA, f2v, -M));

    const char* pkbase = (const char*)pack
        + ((size_t)(b * 32 + jq * 8)) * 16384
        + (size_t)w * 2048
        + (size_t)lane * 16;

    f32x4 acc[8];
    #pragma unroll
    for (int D = 0; D < 8; ++D) acc[D] = (f32x4){0.f, 0.f, 0.f, 0.f};
    f32x4 accd = {0.f, 0.f, 0.f, 0.f};
    union { __bf16 e[8]; bf16x8 v; } ones;
    #pragma unroll
    for (int x = 0; x < 8; ++x) ones.e[x] = (__bf16)1.0f;
    const bf16x8 onesv = ones.v;

    // prologue: tiles 0 and 1 staged; full drain ONCE (us/vs + both DMAs)
    STAGE(0, 0);
    STAGE(1, 1);
    __syncthreads();

    #pragma unroll
    for (int t = 0; t < 16; ++t) {
        const int cb = t % 3;

        // issue STAGE(t+2) into buffer (t+2)%3 = (t-1)%3 — its readers
        // finished before the end-of-(t-1) barrier.
        if (t + 2 <= 15) STAGE(t + 2, (t + 2) % 3);

        // ---- P(t): 8 exp-free values from the register mask ----
        const unsigned wd = (t >> 2) == 0 ? mask.x : (t >> 2) == 1 ? mask.y
                          : (t >> 2) == 2 ? mask.z : mask.w;
        const unsigned byte = (wd >> ((t & 3) << 3)) & 0xffu;
        const float4 u0 = *(const float4*)&us[t * 32 + (kg << 3)];
        const float4 u1 = *(const float4*)&us[t * 32 + (kg << 3) + 4];
        const float4 v0 = *(const float4*)&vs[t * 32 + (kg << 3)];
        const float4 v1 = *(const float4*)&vs[t * 32 + (kg << 3) + 4];
        union { __bf16 e[8]; bf16x8 v; } pa;
        pa.e[0] = (byte &   1u) ? (__bf16)fmaxf(ai_ * u0.x, bi_ * v0.x) : (__bf16)0.f;
        pa.e[1] = (byte &   2u) ? (__bf16)fmaxf(ai_ * u0.y, bi_ * v0.y) : (__bf16)0.f;
        pa.e[2] = (byte &   4u) ? (__bf16)fmaxf(ai_ * u0.z, bi_ * v0.z) : (__bf16)0.f;
        pa.e[3] = (byte &   8u) ? (__bf16)fmaxf(ai_ * u0.w, bi_ * v0.w) : (__bf16)0.f;
        pa.e[4] = (byte &  16u) ? (__bf16)fmaxf(ai_ * u1.x, bi_ * v1.x) : (__bf16)0.f;
        pa.e[5] = (byte &  32u) ? (__bf16)fmaxf(ai_ * u1.y, bi_ * v1.y) : (__bf16)0.f;
        pa.e[6] = (byte &  64u) ? (__bf16)fmaxf(ai_ * u1.z, bi_ * v1.z) : (__bf16)0.f;
        pa.e[7] = (byte & 128u) ? (__bf16)fmaxf(ai_ * u1.w, bi_ * v1.w) : (__bf16)0.f;

        // ---- 9 MFMAs (B from LDS; STAGE(t) done per end-of-(t-1) wait) ----
        __builtin_amdgcn_s_setprio(1);
        #pragma unroll
        for (int D = 0; D < 8; ++D) {
            bf16x8 Bf = *(const bf16x8*)&Bs[cb][(D << 9) + (lane << 3)];
            acc[D] = __builtin_amdgcn_mfma_f32_16x16x32_bf16(pa.v, Bf, acc[D], 0, 0, 0);
        }
        accd = __builtin_amdgcn_mfma_f32_16x16x32_bf16(pa.v, onesv, accd, 0, 0, 0);
        __builtin_amdgcn_s_setprio(0);

        // ---- end-of-iter: counted wait (never drains newest DMA) + RAW barrier
        if (t < 15) {
            if (t < 14) asm volatile("s_waitcnt vmcnt(1)" ::: "memory");
            else        asm volatile("s_waitcnt vmcnt(0)" ::: "memory");
            __builtin_amdgcn_s_barrier();
            asm volatile("" ::: "memory");
        }
    }

    // ---- write partials: C row = kg*4+r, col = il (+ D*16) ----
    const int rowg = (b << 11) + i0 + (w << 4) + (kg << 2);
    if (jq == 0) {
        #pragma unroll
        for (int r = 0; r < 4; ++r) {
            const size_t base = (((size_t)rowg + r) << 7) + il;
            #pragma unroll
            for (int D = 0; D < 8; ++D)
                out[base + (D << 4)] = acc[D][r];
        }
    } else {
        __bf16* po = pO + ((size_t)(jq - 1) << 21);
        #pragma unroll
        for (int r = 0; r < 4; ++r) {
            const size_t base = (((size_t)rowg + r) << 7) + il;
            #pragma unroll
            for (int D = 0; D < 8; ++D)
                po[base + (D << 4)] = (__bf16)acc[D][r];
        }
    }
    if (il == 0) {
        #pragma unroll
        for (int r = 0; r < 4; ++r)
            pD[(jq << 14) + rowg + r] = accd[r];
    }
}

// ---------------------------------------------------------------------------
// Kernel 5: combine 4 j-quarter partials, normalize, elu, residual.
// io aliases out (jq=0 partial): read-before-write per element, same thread.
// ---------------------------------------------------------------------------
__global__ __launch_bounds__(256) void gat_combine(
    float* io, const __bf16* __restrict__ pO,
    const float* __restrict__ pD, const __bf16* __restrict__ hb)
{
    const int idx = blockIdx.x * 256 + threadIdx.x;
    const size_t base = (size_t)idx << 3;
    const int rowAll = idx >> 4;
    const float den = pD[rowAll] + pD[16384 + rowAll]
                    + pD[32768 + rowAll] + pD[49152 + rowAll];
    const float rden = 1.0f / den;
    float4 o0a = *(const float4*)(io + base);
    float4 o0b = *(const float4*)(io + base + 4);
    bf16x8 p1 = *(const bf16x8*)(pO + base);
    bf16x8 p2 = *(const bf16x8*)(pO + (1u << 21) + base);
    bf16x8 p3 = *(const bf16x8*)(pO + (2u << 21) + base);
    bf16x8 hv = *(const bf16x8*)(hb + base);
    float res[8];
    #pragma unroll
    for (int e = 0; e < 8; ++e) {
        float o = ((e < 4) ? ((const float*)&o0a)[e] : ((const float*)&o0b)[e - 4])
                + (float)p1[e] + (float)p2[e] + (float)p3[e];
        float v  = o * rden;
        float el = (v > 0.f) ? v : (fexp2(v * LOG2E) - 1.f);
        res[e] = el + (float)hv[e];
    }
    *(float4*)(io + base)     = (float4){res[0], res[1], res[2], res[3]};
    *(float4*)(io + base + 4) = (float4){res[4], res[5], res[6], res[7]};
}

// ---------------------------------------------------------------------------
extern "C" void kernel_launch(void* const* d_in, const int* in_sizes, int n_in,
                              void* d_out, int out_size, void* d_ws, size_t ws_size,
                              hipStream_t stream)
{
    const float* inp = (const float*)d_in[0];
    const int*   adj = (const int*)d_in[1];
    const float* W   = (const float*)d_in[2];
    const float* a   = (const float*)d_in[3];
    float* out = (float*)d_out;

    // workspace layout (~24.6 MB)
    char* ws = (char*)d_ws;
    __bf16* hb    = (__bf16*)ws;                          // 4 MB
    __bf16* pack  = (__bf16*)(ws + (4 << 20));            // 4 MB
    uint4*  tb    = (uint4*)(ws + (8 << 20));             // 4 MB bitmask
    __bf16* pO    = (__bf16*)(ws + (12 << 20));           // 12 MB (3 bf16 partials)
    float*  pD    = (float*)(ws + (24 << 20));            // 256 KB
    float*  f1    = (float*)(ws + (24 << 20) + 262144);   // 64 KB
    float*  f2    = (float*)(ws + (24 << 20) + 262144 + 65536);
    float*  f1max = (float*)(ws + (24 << 20) + 262144 + 131072);

    gat_adjpack<<<1024, 256, 0, stream>>>(adj, tb);
    gat_prep<<<2048, 128, 0, stream>>>(inp, W, a, hb, f1, f2);
    gat_f1max<<<8, 256, 0, stream>>>(f1, f1max);
    gat_pack<<<512, 256, 0, stream>>>(hb, pack);
    gat_attn16<<<512, 512, 0, stream>>>(tb, pack, f1, f2, f1max, out, pO, pD);
    gat_combine<<<1024, 256, 0, stream>>>(out, pO, pD, hb);
}

// Round 19
// 75.204 us; speedup vs baseline: 5.4096x; 1.0182x over previous
//
#include <hip/hip_runtime.h>
#include <hip/hip_bf16.h>

typedef __bf16 bf16x8 __attribute__((ext_vector_type(8)));
typedef float  f32x4  __attribute__((ext_vector_type(4)));

#define LRELU_ALPHA 0.2f
#define LOG2E 1.44269504088896340736f

__device__ __forceinline__ float fexp2(float x) {
#if __has_builtin(__builtin_amdgcn_exp2f)
    return __builtin_amdgcn_exp2f(x);
#else
    float r; asm("v_exp_f32 %0, %1" : "=v"(r) : "v"(x)); return r;
#endif
}

// ---------------------------------------------------------------------------
// Kernel 1: h = inp @ W (8 rows/block) -> hb (bf16), f1/f2 prescaled by log2e.
// ---------------------------------------------------------------------------
__global__ __launch_bounds__(128) void gat_prep(
    const float* __restrict__ inp, const float* __restrict__ W,
    const float* __restrict__ a,
    __bf16* __restrict__ hb, float* __restrict__ f1, float* __restrict__ f2)
{
    const int r0 = blockIdx.x << 3;
    const int d  = threadIdx.x;
    __shared__ float sIn[8][128];
    __shared__ float sRed[8][4];
    #pragma unroll
    for (int r = 0; r < 8; ++r)
        sIn[r][d] = inp[(size_t)(r0 + r) * 128 + d];
    __syncthreads();

    float acc[8] = {0.f,0.f,0.f,0.f,0.f,0.f,0.f,0.f};
    #pragma unroll 4
    for (int k = 0; k < 128; ++k) {
        float wv = W[k * 128 + d];
        #pragma unroll
        for (int r = 0; r < 8; ++r) acc[r] += sIn[r][k] * wv;
    }

    const float a1 = a[d], a2 = a[128 + d];
    const int wv = d >> 6;
    #pragma unroll
    for (int r = 0; r < 8; ++r) {
        hb[(size_t)(r0 + r) * 128 + d] = (__bf16)acc[r];
        float t1 = acc[r] * a1;
        float t2 = acc[r] * a2;
        #pragma unroll
        for (int m = 1; m < 64; m <<= 1) {
            t1 += __shfl_xor(t1, m);
            t2 += __shfl_xor(t2, m);
        }
        if ((d & 63) == 0) { sRed[r][wv] = t1; sRed[r][2 + wv] = t2; }
    }
    __syncthreads();
    if (d < 8) {
        f1[r0 + d] = (sRed[d][0] + sRed[d][1]) * LOG2E;
        f2[r0 + d] = (sRed[d][2] + sRed[d][3]) * LOG2E;
    }
}

// ---------------------------------------------------------------------------
// Kernel 2: per-batch max of (prescaled) f1
// ---------------------------------------------------------------------------
__global__ __launch_bounds__(256) void gat_f1max(
    const float* __restrict__ f1, float* __restrict__ f1max)
{
    const int b = blockIdx.x;
    const int t = threadIdx.x;
    float m = -1e30f;
    for (int j = t; j < 2048; j += 256) m = fmaxf(m, f1[b * 2048 + j]);
    #pragma unroll
    for (int k = 1; k < 64; k <<= 1) m = fmaxf(m, __shfl_xor(m, k));
    __shared__ float sm[4];
    if ((t & 63) == 0) sm[t >> 6] = m;
    __syncthreads();
    if (t == 0) f1max[b] = fmaxf(fmaxf(sm[0], sm[1]), fmaxf(sm[2], sm[3]));
}

// ---------------------------------------------------------------------------
// Kernel 3: hb -> pack (fragment-major bf16 B-operands); see v5 comment.
// ---------------------------------------------------------------------------
__global__ __launch_bounds__(256) void gat_pack(
    const __bf16* __restrict__ hb, __bf16* __restrict__ pack)
{
    __shared__ __bf16 tile[64][72];
    const int tid = threadIdx.x;
    const int bidx = blockIdx.x;         // 512 blocks
    const int b  = bidx >> 6;
    const int tI = bidx & 63;
    const int n0 = (tI >> 1) << 6;
    const int d0 = (tI & 1) << 6;
    #pragma unroll
    for (int pass = 0; pass < 2; ++pass) {
        int row = (tid >> 3) + (pass << 5);
        int c   = (tid & 7) << 3;
        *(bf16x8*)&tile[row][c] =
            *(const bf16x8*)(hb + (size_t)(b * 2048 + n0 + row) * 128 + d0 + c);
    }
    __syncthreads();
    const int lane = tid & 63;
    const int il = lane & 15;
    const int kg = lane >> 4;
    #pragma unroll
    for (int pass = 0; pass < 2; ++pass) {
        const int f  = (tid >> 6) + (pass << 2);
        const int Dl = f >> 1;
        const int jh = f & 1;
        union { __bf16 e[8]; bf16x8 v; } u;
        #pragma unroll
        for (int e = 0; e < 8; ++e)
            u.e[e] = tile[(jh << 5) + (kg << 3) + e][(Dl << 4) + il];
        const size_t off = (((size_t)(b << 5) + (n0 >> 6)) << 13)
                         + ((size_t)((((d0 >> 4) + Dl) << 1) | jh) << 9)
                         + (lane << 3);
        *(bf16x8*)(pack + off) = u.v;
    }
}

// ---------------------------------------------------------------------------
// Kernel 3b: adj (128 MB) -> tb consumer-major bitmask (4 MB). (passed)
// ---------------------------------------------------------------------------
__global__ __launch_bounds__(256, 4) void gat_adjpack(
    const int* __restrict__ adj, uint4* __restrict__ tb)
{
    const int tid  = threadIdx.x;
    const int rloc = tid >> 4;
    const int jq   = (tid >> 2) & 3;
    const int kg   = tid & 3;
    const size_t grow = (size_t)blockIdx.x * 16 + rloc;   // 1024 blocks
    const int* base = adj + (grow << 11) + (jq << 9) + (kg << 3);

    int4 A[8], B[8];
    #pragma unroll
    for (int i = 0; i < 8; ++i)
        A[i] = *(const int4*)(base + (i >> 1) * 32 + (i & 1) * 4);
    #pragma unroll
    for (int i = 0; i < 8; ++i)
        B[i] = *(const int4*)(base + 128 + (i >> 1) * 32 + (i & 1) * 4);

    unsigned wds[4];
    #pragma unroll
    for (int W = 0; W < 4; ++W) {
        unsigned u = 0;
        #pragma unroll
        for (int i = 0; i < 8; ++i) {
            int4 v = (W & 1) ? B[i] : A[i];
            const int sh = (i >> 1) * 8 + (i & 1) * 4;
            u |= ((unsigned)(v.x > 0) << sh)
               | ((unsigned)(v.y > 0) << (sh + 1))
               | ((unsigned)(v.z > 0) << (sh + 2))
               | ((unsigned)(v.w > 0) << (sh + 3));
        }
        wds[W] = u;
        if (W < 2) {
            #pragma unroll
            for (int i = 0; i < 8; ++i) {
                int4 nv = *(const int4*)(base + (W + 2) * 128 + (i >> 1) * 32 + (i & 1) * 4);
                if (W & 1) B[i] = nv; else A[i] = nv;
            }
        }
    }
    uint4 o; o.x = wds[0]; o.y = wds[1]; o.z = wds[2]; o.w = wds[3];
    tb[((grow << 2) + jq) * 4 + kg] = o;
}

// ---------------------------------------------------------------------------
// Kernel 4 v17: whole-panel LDS + BARRIER-FREE main loop.
// Grid 256 = 8 batch x 8 rowgroups(256 rows) x 4 j-quarters; 1024 thr (16
// waves, 1 block/CU). Prologue: stage the full 128 KB B panel (8x
// global_load_lds per thread) + ONE __syncthreads. Loop (16 iters): P once
// per lane (exp-free, bitmask adj), 8 conflict-free ds_read_b128, 9 MFMAs —
// ZERO synchronization. Dynamic LDS 132 KB.
// ---------------------------------------------------------------------------
__global__ __launch_bounds__(1024, 4) void gat_attn17(
    const uint4* __restrict__ tb, const __bf16* __restrict__ pack,
    const float* __restrict__ f1g, const float* __restrict__ f2g,
    const float* __restrict__ f1maxg,
    float* __restrict__ out, __bf16* __restrict__ pO, float* __restrict__ pD)
{
    extern __shared__ char smem[];
    __bf16* Bs = (__bf16*)smem;                       // 128 KB panel
    float*  us = (float*)(smem + 131072);             // 2 KB
    float*  vs = (float*)(smem + 131072 + 2048);      // 2 KB

    const int bid = ((blockIdx.x & 7) << 5) | (blockIdx.x >> 3);  // batch<->XCD
    const int b  = bid >> 5;
    const int rg = (bid >> 2) & 7;
    const int jq = bid & 3;
    const int i0 = rg << 8;              // 256 rows per block
    const int jb = jq << 9;              // 512-j quarter
    const int tid = threadIdx.x;

    const int w    = tid >> 6;           // wave 0..15 -> rows w*16..+16
    const int lane = tid & 63;
    const int il   = lane & 15;
    const int kg   = lane >> 4;
    const int row  = i0 + (w << 4) + il;
    const size_t grow = (size_t)(b << 11) + row;

    // ---- stage the full B panel: 8 x 16B per thread, wave-linear ----
    // panel = pack bytes [(b*32 + jq*8)*16384 , +131072)
    const char* psrc = (const char*)pack + ((size_t)(b * 32 + jq * 8)) * 16384;
#if __has_builtin(__builtin_amdgcn_global_load_lds)
    #pragma unroll
    for (int k = 0; k < 8; ++k) {
        __builtin_amdgcn_global_load_lds(
            (const __attribute__((address_space(1))) void*)
                (psrc + k * 16384 + w * 1024 + lane * 16),
            (__attribute__((address_space(3))) void*)
                ((char*)Bs + k * 16384 + w * 1024),
            16, 0, 0);
    }
#else
    #pragma unroll
    for (int k = 0; k < 8; ++k) {
        bf16x8 tmp = *(const bf16x8*)(psrc + k * 16384 + w * 1024 + lane * 16);
        *(bf16x8*)((char*)Bs + k * 16384 + w * 1024 + lane * 16) = tmp;
    }
#endif

    // entire adj need: ONE uint4 (128 bits = 16 iters x 8 j)
    const uint4 mask = tb[((grow << 2) + jq) * 4 + kg];

    // j-side tables (this quarter)
    if (tid < 128) {
        float4 fv = *(const float4*)&f1g[(b << 11) + jb + (tid << 2)];
        float4 uu, vv;
        uu.x = fexp2(fv.x); uu.y = fexp2(fv.y);
        uu.z = fexp2(fv.z); uu.w = fexp2(fv.w);
        vv.x = fexp2(LRELU_ALPHA * fv.x); vv.y = fexp2(LRELU_ALPHA * fv.y);
        vv.z = fexp2(LRELU_ALPHA * fv.z); vv.w = fexp2(LRELU_ALPHA * fv.w);
        *(float4*)&us[tid << 2] = uu;
        *(float4*)&vs[tid << 2] = vv;
    }

    // per-lane P factors
    const float fm  = f1maxg[b];
    const float f2v = f2g[grow];
    const float zM  = f2v + fm;
    const float M   = fmaxf(zM, LRELU_ALPHA * zM);        // exact: p <= 1
    const float ai_ = fexp2(f2v - M);
    const float bi_ = fexp2(__builtin_fmaf(LRELU_ALPHA, f2v, -M));

    f32x4 acc[8];
    #pragma unroll
    for (int D = 0; D < 8; ++D) acc[D] = (f32x4){0.f, 0.f, 0.f, 0.f};
    f32x4 accd = {0.f, 0.f, 0.f, 0.f};
    union { __bf16 e[8]; bf16x8 v; } ones;
    #pragma unroll
    for (int x = 0; x < 8; ++x) ones.e[x] = (__bf16)1.0f;
    const bf16x8 onesv = ones.v;

    __syncthreads();                     // panel + us/vs ready (ONLY barrier)

    #pragma unroll
    for (int t = 0; t < 16; ++t) {
        // ---- P(t): 8 exp-free values from the register mask ----
        const unsigned wd = (t >> 2) == 0 ? mask.x : (t >> 2) == 1 ? mask.y
                          : (t >> 2) == 2 ? mask.z : mask.w;
        const unsigned byte = (wd >> ((t & 3) << 3)) & 0xffu;
        const float4 u0 = *(const float4*)&us[t * 32 + (kg << 3)];
        const float4 u1 = *(const float4*)&us[t * 32 + (kg << 3) + 4];
        const float4 v0 = *(const float4*)&vs[t * 32 + (kg << 3)];
        const float4 v1 = *(const float4*)&vs[t * 32 + (kg << 3) + 4];
        union { __bf16 e[8]; bf16x8 v; } pa;
        pa.e[0] = (byte &   1u) ? (__bf16)fmaxf(ai_ * u0.x, bi_ * v0.x) : (__bf16)0.f;
        pa.e[1] = (byte &   2u) ? (__bf16)fmaxf(ai_ * u0.y, bi_ * v0.y) : (__bf16)0.f;
        pa.e[2] = (byte &   4u) ? (__bf16)fmaxf(ai_ * u0.z, bi_ * v0.z) : (__bf16)0.f;
        pa.e[3] = (byte &   8u) ? (__bf16)fmaxf(ai_ * u0.w, bi_ * v0.w) : (__bf16)0.f;
        pa.e[4] = (byte &  16u) ? (__bf16)fmaxf(ai_ * u1.x, bi_ * v1.x) : (__bf16)0.f;
        pa.e[5] = (byte &  32u) ? (__bf16)fmaxf(ai_ * u1.y, bi_ * v1.y) : (__bf16)0.f;
        pa.e[6] = (byte &  64u) ? (__bf16)fmaxf(ai_ * u1.z, bi_ * v1.z) : (__bf16)0.f;
        pa.e[7] = (byte & 128u) ? (__bf16)fmaxf(ai_ * u1.w, bi_ * v1.w) : (__bf16)0.f;

        // ---- 9 MFMAs; B frag (t,D) at byte (t>>1)*16384 + (D*2+(t&1))*1024
        const char* bbase = (const char*)Bs + (t >> 1) * 16384
                          + (t & 1) * 1024 + lane * 16;
        __builtin_amdgcn_s_setprio(1);
        #pragma unroll
        for (int D = 0; D < 8; ++D) {
            bf16x8 Bf = *(const bf16x8*)(bbase + D * 2048);
            acc[D] = __builtin_amdgcn_mfma_f32_16x16x32_bf16(pa.v, Bf, acc[D], 0, 0, 0);
        }
        accd = __builtin_amdgcn_mfma_f32_16x16x32_bf16(pa.v, onesv, accd, 0, 0, 0);
        __builtin_amdgcn_s_setprio(0);
    }

    // ---- write partials: C row = kg*4+r, col = il (+ D*16) ----
    const int rowg = (b << 11) + i0 + (w << 4) + (kg << 2);
    if (jq == 0) {
        #pragma unroll
        for (int r = 0; r < 4; ++r) {
            const size_t base = (((size_t)rowg + r) << 7) + il;
            #pragma unroll
            for (int D = 0; D < 8; ++D)
                out[base + (D << 4)] = acc[D][r];
        }
    } else {
        __bf16* po = pO + ((size_t)(jq - 1) << 21);
        #pragma unroll
        for (int r = 0; r < 4; ++r) {
            const size_t base = (((size_t)rowg + r) << 7) + il;
            #pragma unroll
            for (int D = 0; D < 8; ++D)
                po[base + (D << 4)] = (__bf16)acc[D][r];
        }
    }
    if (il == 0) {
        #pragma unroll
        for (int r = 0; r < 4; ++r)
            pD[(jq << 14) + rowg + r] = accd[r];
    }
}

// ---------------------------------------------------------------------------
// Kernel 5: combine 4 j-quarter partials, normalize, elu, residual.
// io aliases out (jq=0 partial): read-before-write per element, same thread.
// ---------------------------------------------------------------------------
__global__ __launch_bounds__(256) void gat_combine(
    float* io, const __bf16* __restrict__ pO,
    const float* __restrict__ pD, const __bf16* __restrict__ hb)
{
    const int idx = blockIdx.x * 256 + threadIdx.x;
    const size_t base = (size_t)idx << 3;
    const int rowAll = idx >> 4;
    const float den = pD[rowAll] + pD[16384 + rowAll]
                    + pD[32768 + rowAll] + pD[49152 + rowAll];
    const float rden = 1.0f / den;
    float4 o0a = *(const float4*)(io + base);
    float4 o0b = *(const float4*)(io + base + 4);
    bf16x8 p1 = *(const bf16x8*)(pO + base);
    bf16x8 p2 = *(const bf16x8*)(pO + (1u << 21) + base);
    bf16x8 p3 = *(const bf16x8*)(pO + (2u << 21) + base);
    bf16x8 hv = *(const bf16x8*)(hb + base);
    float res[8];
    #pragma unroll
    for (int e = 0; e < 8; ++e) {
        float o = ((e < 4) ? ((const float*)&o0a)[e] : ((const float*)&o0b)[e - 4])
                + (float)p1[e] + (float)p2[e] + (float)p3[e];
        float v  = o * rden;
        float el = (v > 0.f) ? v : (fexp2(v * LOG2E) - 1.f);
        res[e] = el + (float)hv[e];
    }
    *(float4*)(io + base)     = (float4){res[0], res[1], res[2], res[3]};
    *(float4*)(io + base + 4) = (float4){res[4], res[5], res[6], res[7]};
}

// ---------------------------------------------------------------------------
extern "C" void kernel_launch(void* const* d_in, const int* in_sizes, int n_in,
                              void* d_out, int out_size, void* d_ws, size_t ws_size,
                              hipStream_t stream)
{
    const float* inp = (const float*)d_in[0];
    const int*   adj = (const int*)d_in[1];
    const float* W   = (const float*)d_in[2];
    const float* a   = (const float*)d_in[3];
    float* out = (float*)d_out;

    // workspace layout (~24.6 MB)
    char* ws = (char*)d_ws;
    __bf16* hb    = (__bf16*)ws;                          // 4 MB
    __bf16* pack  = (__bf16*)(ws + (4 << 20));            // 4 MB
    uint4*  tb    = (uint4*)(ws + (8 << 20));             // 4 MB bitmask
    __bf16* pO    = (__bf16*)(ws + (12 << 20));           // 12 MB (3 bf16 partials)
    float*  pD    = (float*)(ws + (24 << 20));            // 256 KB
    float*  f1    = (float*)(ws + (24 << 20) + 262144);   // 64 KB
    float*  f2    = (float*)(ws + (24 << 20) + 262144 + 65536);
    float*  f1max = (float*)(ws + (24 << 20) + 262144 + 131072);

    // allow 132 KB dynamic LDS for the attention kernel (idempotent)
    hipFuncSetAttribute((const void*)gat_attn17,
                        hipFuncAttributeMaxDynamicSharedMemorySize, 135168);

    gat_adjpack<<<1024, 256, 0, stream>>>(adj, tb);
    gat_prep<<<2048, 128, 0, stream>>>(inp, W, a, hb, f1, f2);
    gat_f1max<<<8, 256, 0, stream>>>(f1, f1max);
    gat_pack<<<512, 256, 0, stream>>>(hb, pack);
    gat_attn17<<<256, 1024, 135168, stream>>>(tb, pack, f1, f2, f1max, out, pO, pD);
    gat_combine<<<1024, 256, 0, stream>>>(out, pO, pD, hb);
}